// Round 1
// baseline (477.579 us; speedup 1.0000x reference)
//
#include <hip/hip_runtime.h>
#include <hip/hip_bf16.h>

#define N_ROWS 8192
#define DIM 256

typedef __attribute__((ext_vector_type(4))) float f32x4;
typedef __attribute__((ext_vector_type(8))) short bf16x8;

// ---------------- Kernel A: normalize rows, split into bf16 hi/lo ----------------
__global__ __launch_bounds__(256) void prep_kernel(const float* __restrict__ feat,
                                                   ushort* __restrict__ fhi,
                                                   ushort* __restrict__ flo) {
    const int row = blockIdx.x;
    const int tid = threadIdx.x;
    float x = feat[(size_t)row * DIM + tid];
    float ss = x * x;
#pragma unroll
    for (int off = 32; off; off >>= 1) ss += __shfl_down(ss, off);
    __shared__ float red[4];
    __shared__ float s_inv;
    const int wid = tid >> 6;
    if ((tid & 63) == 0) red[wid] = ss;
    __syncthreads();
    if (tid == 0) {
        float tot = red[0] + red[1] + red[2] + red[3];
        float nrm = sqrtf(tot);
        s_inv = 1.0f / fmaxf(nrm, 1e-12f);
    }
    __syncthreads();
    float v = x * s_inv;
    __hip_bfloat16 h = __float2bfloat16(v);
    float hf = __bfloat162float(h);
    __hip_bfloat16 l = __float2bfloat16(v - hf);
    fhi[(size_t)row * DIM + tid] = *reinterpret_cast<ushort*>(&h);
    flo[(size_t)row * DIM + tid] = *reinterpret_cast<ushort*>(&l);
}

// ---------------- Kernel B: fused sim + mask + online softmax ----------------
// grid = 256 blocks (32 rows each), block = 512 threads (8 waves)
// wave w: row-tile (w&1) of 16 rows, col-stripe (w>>1) of 512/4 col-tiles
__global__ __launch_bounds__(512) void main_kernel(const ushort* __restrict__ fhi,
                                                   const ushort* __restrict__ flo,
                                                   const float* __restrict__ ious,
                                                   const int* __restrict__ labels,
                                                   float* __restrict__ loss_arr,
                                                   float* __restrict__ valid_arr) {
    const int tid  = threadIdx.x;
    const int lane = tid & 63;
    const int w    = tid >> 6;     // 0..7
    const int rt   = w & 1;        // row-tile within block
    const int cs   = w >> 1;       // col stripe 0..3
    const int rb   = blockIdx.x * 32;
    const int r0   = rb + rt * 16;

    const int lrow = lane & 15;
    const int kgrp = lane >> 4;    // 0..3

    // A fragments: 16 rows x 256 k, hi and lo (held in registers)
    bf16x8 ahi[8], alo[8];
    {
        const ushort* pa = fhi + (size_t)(r0 + lrow) * DIM + kgrp * 8;
        const ushort* pb = flo + (size_t)(r0 + lrow) * DIM + kgrp * 8;
#pragma unroll
        for (int t = 0; t < 8; ++t) {
            ahi[t] = *reinterpret_cast<const bf16x8*>(pa + t * 32);
            alo[t] = *reinterpret_cast<const bf16x8*>(pb + t * 32);
        }
    }

    // Metadata for the 4 rows this lane's accumulator covers:
    // C/D layout: col = lane&15, row = (lane>>4)*4 + reg   [HW-verified]
    int labi[4]; float ioui[4];
#pragma unroll
    for (int r = 0; r < 4; ++r) {
        int gi = r0 + kgrp * 4 + r;
        labi[r] = labels[gi];
        ioui[r] = ious[gi];
    }

    // per-lane online softmax state (each lane owns one column-slice of 4 rows)
    float M[4], ps[4], as_[4];
    int anyp[4], anyn[4];
#pragma unroll
    for (int r = 0; r < 4; ++r) { M[r] = -1e30f; ps[r] = 0.f; as_[r] = 0.f; anyp[r] = 0; anyn[r] = 0; }

    for (int jt = cs; jt < N_ROWS / 16; jt += 4) {
        const int jc = jt * 16;
        const int colg = jc + lrow;

        bf16x8 bhi[8], blo[8];
        {
            const ushort* pa = fhi + (size_t)colg * DIM + kgrp * 8;
            const ushort* pb = flo + (size_t)colg * DIM + kgrp * 8;
#pragma unroll
            for (int t = 0; t < 8; ++t) {
                bhi[t] = *reinterpret_cast<const bf16x8*>(pa + t * 32);
                blo[t] = *reinterpret_cast<const bf16x8*>(pb + t * 32);
            }
        }

        f32x4 acc = {0.f, 0.f, 0.f, 0.f};
#pragma unroll
        for (int t = 0; t < 8; ++t) {
            acc = __builtin_amdgcn_mfma_f32_16x16x32_bf16(ahi[t], bhi[t], acc, 0, 0, 0);
            acc = __builtin_amdgcn_mfma_f32_16x16x32_bf16(ahi[t], blo[t], acc, 0, 0, 0);
            acc = __builtin_amdgcn_mfma_f32_16x16x32_bf16(alo[t], bhi[t], acc, 0, 0, 0);
        }

        // epilogue: mask + online softmax update
        const int   labj = labels[colg];
        const float iouj = ious[colg];
        const bool  fgj    = labj >= 0;
        const bool  ioujhi = iouj > 0.5f;
#pragma unroll
        for (int r = 0; r < 4; ++r) {
            const int gi = r0 + kgrp * 4 + r;
            float sim = acc[r] * 10.0f;   // /TAU
            bool same = (labi[r] == labj);
            bool ioum = ioujhi && (ioui[r] > 0.5f) && (fabsf(iouj - ioui[r]) < 0.2f);
            bool pf   = (labi[r] >= 0) && fgj;
            bool ns   = (gi != colg);
            bool pos  = same && ioum && pf && ns;
            bool neg  = ((!same) || (ioui[r] < 0.3f)) && pf && ns;
            bool allm = pos || neg;
            float se  = allm ? sim : -1e30f;
            float Mn  = fmaxf(M[r], se);
            float scale = __expf(M[r] - Mn);     // ==1 when max unchanged
            float e   = allm ? __expf(se - Mn) : 0.0f;
            ps[r]  = ps[r] * scale + (pos ? e : 0.0f);
            as_[r] = as_[r] * scale + e;
            M[r]   = Mn;
            anyp[r] |= (int)pos;
            anyn[r] |= (int)neg;
        }
    }

    // intra-wave merge: rows live in 16 lanes (xor over bits 0..3)
#pragma unroll
    for (int r = 0; r < 4; ++r) {
#pragma unroll
        for (int off = 1; off < 16; off <<= 1) {
            float Mo  = __shfl_xor(M[r], off);
            float po  = __shfl_xor(ps[r], off);
            float ao  = __shfl_xor(as_[r], off);
            int   apo = __shfl_xor(anyp[r], off);
            int   ano = __shfl_xor(anyn[r], off);
            float Mn = fmaxf(M[r], Mo);
            float s1 = __expf(M[r] - Mn);
            float s2 = __expf(Mo - Mn);
            ps[r]  = ps[r] * s1 + po * s2;
            as_[r] = as_[r] * s1 + ao * s2;
            M[r]   = Mn;
            anyp[r] |= apo; anyn[r] |= ano;
        }
    }

    // cross-wave merge via LDS (4 col-stripes per row-tile)
    __shared__ float lM[8][16], lP[8][16], lA[8][16];
    __shared__ int   lap[8][16], lan[8][16];
    if (lrow == 0) {
#pragma unroll
        for (int r = 0; r < 4; ++r) {
            int rl = kgrp * 4 + r;
            lM[w][rl] = M[r]; lP[w][rl] = ps[r]; lA[w][rl] = as_[r];
            lap[w][rl] = anyp[r]; lan[w][rl] = anyn[r];
        }
    }
    __syncthreads();
    if (tid < 32) {
        const int rtt = tid >> 4, rl = tid & 15;
        float Mm = -1e30f, Pm = 0.f, Am = 0.f;
        int ap = 0, an = 0;
#pragma unroll
        for (int c = 0; c < 4; ++c) {
            int ww = rtt + 2 * c;
            float Mo = lM[ww][rl], Po = lP[ww][rl], Ao = lA[ww][rl];
            float Mn = fmaxf(Mm, Mo);
            float s1 = __expf(Mm - Mn), s2 = __expf(Mo - Mn);
            Pm = Pm * s1 + Po * s2;
            Am = Am * s1 + Ao * s2;
            Mm = Mn;
            ap |= lap[ww][rl]; an |= lan[ww][rl];
        }
        const int gi = rb + tid;
        float psc = fminf(fmaxf(Pm, 1e-6f), 1e6f);
        float asc = fminf(fmaxf(Am, 1e-6f), 1e6f);
        float loss = fminf(__logf(asc) - __logf(psc), 10.0f);
        bool valid = (labels[gi] >= 0) && (ap != 0) && (an != 0);
        loss_arr[gi]  = valid ? loss : 0.0f;
        valid_arr[gi] = valid ? 1.0f : 0.0f;
    }
}

// ---------------- Kernel C: final mean over valid rows ----------------
__global__ __launch_bounds__(256) void reduce_kernel(const float* __restrict__ loss_arr,
                                                     const float* __restrict__ valid_arr,
                                                     float* __restrict__ out) {
    const int tid = threadIdx.x;
    float tl = 0.f, tc = 0.f;
    for (int i = tid; i < N_ROWS; i += 256) { tl += loss_arr[i]; tc += valid_arr[i]; }
#pragma unroll
    for (int off = 32; off; off >>= 1) { tl += __shfl_down(tl, off); tc += __shfl_down(tc, off); }
    __shared__ float sl[4], sc[4];
    const int wid = tid >> 6;
    if ((tid & 63) == 0) { sl[wid] = tl; sc[wid] = tc; }
    __syncthreads();
    if (tid == 0) {
        float T = sl[0] + sl[1] + sl[2] + sl[3];
        float C = sc[0] + sc[1] + sc[2] + sc[3];
        out[0] = (C > 0.f) ? (T / C) : 0.0f;
    }
}

extern "C" void kernel_launch(void* const* d_in, const int* in_sizes, int n_in,
                              void* d_out, int out_size, void* d_ws, size_t ws_size,
                              hipStream_t stream) {
    const float* feat   = (const float*)d_in[0];
    const float* ious   = (const float*)d_in[1];
    const int*   labels = (const int*)d_in[2];
    float* out = (float*)d_out;

    ushort* fhi = (ushort*)d_ws;
    ushort* flo = fhi + (size_t)N_ROWS * DIM;
    float*  loss_arr  = (float*)(flo + (size_t)N_ROWS * DIM);
    float*  valid_arr = loss_arr + N_ROWS;

    prep_kernel<<<N_ROWS, 256, 0, stream>>>(feat, fhi, flo);
    main_kernel<<<N_ROWS / 32, 512, 0, stream>>>(fhi, flo, ious, labels, loss_arr, valid_arr);
    reduce_kernel<<<1, 256, 0, stream>>>(loss_arr, valid_arr, out);
}

// Round 7
// 110.465 us; speedup vs baseline: 4.3234x; 4.3234x over previous
//
#include <hip/hip_runtime.h>
#include <hip/hip_bf16.h>

#define N_ROWS 8192
#define DIM 256
#define R_BLK 128          // rows per block
#define C_CHUNK 1024       // cols per block
#define TILE_C 32          // cols per LDS tile
#define N_CHUNKS 8
#define N_ITERS (C_CHUNK / TILE_C)   // 32

typedef __attribute__((ext_vector_type(4))) float f32x4;
typedef __attribute__((ext_vector_type(8))) short bf16x8;

__device__ __forceinline__ void gload_lds16(const void* g, void* l) {
    using gv = const __attribute__((address_space(1))) void*;
    using sv = __attribute__((address_space(3))) void*;
    __builtin_amdgcn_global_load_lds((gv)g, (sv)l, 16, 0, 0);
}

// ---------------- Kernel A: normalize rows -> bf16 ----------------
__global__ __launch_bounds__(256) void prep_kernel(const float* __restrict__ feat,
                                                   ushort* __restrict__ fhi) {
    const int row = blockIdx.x;
    const int tid = threadIdx.x;
    float x = feat[(size_t)row * DIM + tid];
    float ss = x * x;
#pragma unroll
    for (int off = 32; off; off >>= 1) ss += __shfl_down(ss, off);
    __shared__ float red[4];
    __shared__ float s_inv;
    const int wid = tid >> 6;
    if ((tid & 63) == 0) red[wid] = ss;
    __syncthreads();
    if (tid == 0) {
        float tot = red[0] + red[1] + red[2] + red[3];
        s_inv = 1.0f / fmaxf(sqrtf(tot), 1e-12f);
    }
    __syncthreads();
    __hip_bfloat16 h = __float2bfloat16(x * s_inv);
    fhi[(size_t)row * DIM + tid] = *reinterpret_cast<ushort*>(&h);
}

// ---------------- Kernel B: fused tiled sim + mask + fixed-max softmax partials ----------------
// grid = 512 blocks: chunk = bid&7 (1024 cols), rowblk = bid>>3 (128 rows)
// 8 waves, wave w owns rows rowblk*128 + w*16 .. +15, sweeps all 32 col-tiles of the chunk.
__global__ __launch_bounds__(512, 4) void main_kernel(const ushort* __restrict__ fhi,
                                                      const float* __restrict__ ious,
                                                      const int* __restrict__ labels,
                                                      float* __restrict__ ps_part,
                                                      float* __restrict__ as_part,
                                                      int* __restrict__ flag_part) {
    const int bid   = blockIdx.x;
    const int chunk = bid & 7;
    const int c0    = chunk * C_CHUNK;
    const int rbase = (bid >> 3) * R_BLK;

    const int tid  = threadIdx.x;
    const int lane = tid & 63;
    const int w    = tid >> 6;          // 0..7
    const int lrow = lane & 15;
    const int kg   = lane >> 4;         // 0..3
    const int r0   = rbase + w * 16;

    __shared__ ushort bt[2][TILE_C][DIM];   // 32 KB, double-buffered B tile
    __shared__ int    lab_s[C_CHUNK];       // 4 KB
    __shared__ float  iou_s[C_CHUNK];       // 4 KB

    // stage column metadata for this chunk
#pragma unroll
    for (int i = tid; i < C_CHUNK; i += 512) {
        lab_s[i] = labels[c0 + i];
        iou_s[i] = ious[c0 + i];
    }

    // A fragments: 16 rows x 256 k in registers (32 VGPR)
    bf16x8 av[8];
    {
        const ushort* pa = fhi + (size_t)(r0 + lrow) * DIM + kg * 8;
#pragma unroll
        for (int t = 0; t < 8; ++t) av[t] = *reinterpret_cast<const bf16x8*>(pa + t * 32);
    }

    // row metadata (C/D layout: col=lane&15, row=kg*4+reg)
    int labi[4]; float ioui[4]; bool fgi[4], hi_i[4], ng_i[4];
#pragma unroll
    for (int r = 0; r < 4; ++r) {
        int gi = r0 + kg * 4 + r;
        labi[r] = labels[gi];
        ioui[r] = ious[gi];
        fgi[r]  = labi[r] >= 0;
        hi_i[r] = ioui[r] > 0.5f;
        ng_i[r] = ioui[r] < 0.3f;
    }

    float ps[4] = {0.f, 0.f, 0.f, 0.f};
    float as_[4] = {0.f, 0.f, 0.f, 0.f};
    int apn = 0;   // bits 0-3: any-pos per r, bits 4-7: any-neg per r

    // staging: tile `it` -> buf; linear LDS dest, pre-swizzled global source (rule #21)
    const char* fhib = (const char*)fhi;
    char* btb = (char*)&bt[0][0][0];
    auto stage = [&](int buf, int it) {
        const int jc = c0 + it * TILE_C;
        const int kb = (tid & 31) * 16;
#pragma unroll
        for (int iss = 0; iss < 2; ++iss) {
            const int row = (tid >> 5) + iss * 16;          // tile-local col index
            const char* src = fhib + (((size_t)(jc + row)) << 9) + (kb ^ ((row & 7) << 4));
            char* dst = btb + buf * 16384 + iss * 8192 + tid * 16;
            gload_lds16(src, dst);
        }
    };

    stage(0, 0);
    __syncthreads();

    int cur = 0;
    for (int it = 0; it < N_ITERS; ++it) {
        if (it + 1 < N_ITERS) stage(cur ^ 1, it + 1);

        const int jcl = it * TILE_C;
        const int labj0 = lab_s[jcl + lrow];
        const int labj1 = lab_s[jcl + 16 + lrow];
        const float iouj0 = iou_s[jcl + lrow];
        const float iouj1 = iou_s[jcl + 16 + lrow];

        f32x4 acc0 = {0.f, 0.f, 0.f, 0.f};
        f32x4 acc1 = {0.f, 0.f, 0.f, 0.f};
        const char* base = btb + cur * 16384;
        const int swz = (lrow & 7) << 4;
#pragma unroll
        for (int t = 0; t < 8; ++t) {
            const int koff = kg * 16 + t * 64;
            bf16x8 b0 = *reinterpret_cast<const bf16x8*>(base + lrow * 512 + (koff ^ swz));
            bf16x8 b1 = *reinterpret_cast<const bf16x8*>(base + (lrow + 16) * 512 + (koff ^ swz));
            acc0 = __builtin_amdgcn_mfma_f32_16x16x32_bf16(av[t], b0, acc0, 0, 0, 0);
            acc1 = __builtin_amdgcn_mfma_f32_16x16x32_bf16(av[t], b1, acc1, 0, 0, 0);
        }

        // epilogue: fixed max M=10 (sim <= 10 always); e = exp(sim-10)
#pragma unroll
        for (int half = 0; half < 2; ++half) {
            const int colg = c0 + jcl + half * 16 + lrow;
            const int labj = half ? labj1 : labj0;
            const float iouj = half ? iouj1 : iouj0;
            const f32x4 acc = half ? acc1 : acc0;
            const bool fgj = labj >= 0;
            const bool hij = iouj > 0.5f;
#pragma unroll
            for (int r = 0; r < 4; ++r) {
                const int gi = r0 + kg * 4 + r;
                const float sim = acc[r] * 10.0f;
                const bool same = (labi[r] == labj);
                const bool ioum = hij && hi_i[r] && (fabsf(iouj - ioui[r]) < 0.2f);
                const bool pf   = fgi[r] && fgj;
                const bool ns   = (gi != colg);
                const bool pos  = same && ioum && pf && ns;
                const bool neg  = ((!same) || ng_i[r]) && pf && ns;
                const bool allm = pos || neg;
                const float e = allm ? __expf(sim - 10.0f) : 0.0f;
                as_[r] += e;
                ps[r]  += pos ? e : 0.0f;
                apn |= (pos ? (1 << r) : 0) | (neg ? (1 << (r + 4)) : 0);
            }
        }
        __syncthreads();
        cur ^= 1;
    }

    // reduce over the 16 lanes (lrow) holding col-slices of the same rows
#pragma unroll
    for (int off = 1; off < 16; off <<= 1) {
#pragma unroll
        for (int r = 0; r < 4; ++r) {
            ps[r]  += __shfl_xor(ps[r], off);
            as_[r] += __shfl_xor(as_[r], off);
        }
        apn |= __shfl_xor(apn, off);
    }

    if (lrow == 0) {
#pragma unroll
        for (int r = 0; r < 4; ++r) {
            const int row = r0 + kg * 4 + r;
            const int idx = chunk * N_ROWS + row;
            ps_part[idx]   = ps[r];
            as_part[idx]   = as_[r];
            flag_part[idx] = ((apn >> r) & 1) | (((apn >> (r + 4)) & 1) << 1);
        }
    }
}

// ---------------- Kernel C: combine chunk partials -> per-row loss ----------------
__global__ __launch_bounds__(256) void combine_kernel(const float* __restrict__ ps_part,
                                                      const float* __restrict__ as_part,
                                                      const int* __restrict__ flag_part,
                                                      const int* __restrict__ labels,
                                                      float* __restrict__ loss_arr,
                                                      float* __restrict__ valid_arr) {
    const int row = blockIdx.x * 256 + threadIdx.x;
    float P = 0.f, A = 0.f; int f = 0;
#pragma unroll
    for (int c = 0; c < N_CHUNKS; ++c) {
        P += ps_part[c * N_ROWS + row];
        A += as_part[c * N_ROWS + row];
        f |= flag_part[c * N_ROWS + row];
    }
    const float psc = fminf(fmaxf(P, 1e-6f), 1e6f);
    const float asc = fminf(fmaxf(A, 1e-6f), 1e6f);
    const float loss = fminf(__logf(asc) - __logf(psc), 10.0f);
    const bool valid = (labels[row] >= 0) && (f & 1) && (f & 2);
    loss_arr[row]  = valid ? loss : 0.0f;
    valid_arr[row] = valid ? 1.0f : 0.0f;
}

// ---------------- Kernel D: final mean ----------------
__global__ __launch_bounds__(256) void reduce_kernel(const float* __restrict__ loss_arr,
                                                     const float* __restrict__ valid_arr,
                                                     float* __restrict__ out) {
    const int tid = threadIdx.x;
    float tl = 0.f, tc = 0.f;
    for (int i = tid; i < N_ROWS; i += 256) { tl += loss_arr[i]; tc += valid_arr[i]; }
#pragma unroll
    for (int off = 32; off; off >>= 1) { tl += __shfl_down(tl, off); tc += __shfl_down(tc, off); }
    __shared__ float sl[4], sc[4];
    const int wid = tid >> 6;
    if ((tid & 63) == 0) { sl[wid] = tl; sc[wid] = tc; }
    __syncthreads();
    if (tid == 0) {
        float T = sl[0] + sl[1] + sl[2] + sl[3];
        float C = sc[0] + sc[1] + sc[2] + sc[3];
        out[0] = (C > 0.f) ? (T / C) : 0.0f;
    }
}

extern "C" void kernel_launch(void* const* d_in, const int* in_sizes, int n_in,
                              void* d_out, int out_size, void* d_ws, size_t ws_size,
                              hipStream_t stream) {
    const float* feat   = (const float*)d_in[0];
    const float* ious   = (const float*)d_in[1];
    const int*   labels = (const int*)d_in[2];
    float* out = (float*)d_out;

    ushort* fhi = (ushort*)d_ws;                                   // 4 MB
    float*  ps_part = (float*)(fhi + (size_t)N_ROWS * DIM);        // 256 KB
    float*  as_part = ps_part + (size_t)N_CHUNKS * N_ROWS;         // 256 KB
    int*    flag_part = (int*)(as_part + (size_t)N_CHUNKS * N_ROWS); // 256 KB
    float*  loss_arr  = (float*)(flag_part + (size_t)N_CHUNKS * N_ROWS);
    float*  valid_arr = loss_arr + N_ROWS;

    prep_kernel<<<N_ROWS, 256, 0, stream>>>(feat, fhi);
    main_kernel<<<(N_ROWS / R_BLK) * N_CHUNKS, 512, 0, stream>>>(fhi, ious, labels,
                                                                 ps_part, as_part, flag_part);
    combine_kernel<<<N_ROWS / 256, 256, 0, stream>>>(ps_part, as_part, flag_part, labels,
                                                     loss_arr, valid_arr);
    reduce_kernel<<<1, 256, 0, stream>>>(loss_arr, valid_arr, out);
}

// Round 11
// 104.446 us; speedup vs baseline: 4.5725x; 1.0576x over previous
//
#include <hip/hip_runtime.h>
#include <hip/hip_bf16.h>

#define N_ROWS 8192
#define DIM 256
#define R_BLK 128          // rows per block
#define C_CHUNK 512        // cols per block
#define TILE_C 32          // cols per LDS tile
#define N_CHUNKS 16
#define N_ITERS (C_CHUNK / TILE_C)   // 16

typedef __attribute__((ext_vector_type(4))) float f32x4;
typedef __attribute__((ext_vector_type(8))) short bf16x8;

__device__ __forceinline__ void gload_lds16(const void* g, void* l) {
    using gv = const __attribute__((address_space(1))) void*;
    using sv = __attribute__((address_space(3))) void*;
    __builtin_amdgcn_global_load_lds((gv)g, (sv)l, 16, 0, 0);
}

// ---------------- Kernel A: normalize rows -> bf16 ----------------
__global__ __launch_bounds__(256) void prep_kernel(const float* __restrict__ feat,
                                                   ushort* __restrict__ fhi) {
    const int row = blockIdx.x;
    const int tid = threadIdx.x;
    float x = feat[(size_t)row * DIM + tid];
    float ss = x * x;
#pragma unroll
    for (int off = 32; off; off >>= 1) ss += __shfl_down(ss, off);
    __shared__ float red[4];
    __shared__ float s_inv;
    const int wid = tid >> 6;
    if ((tid & 63) == 0) red[wid] = ss;
    __syncthreads();
    if (tid == 0) {
        float tot = red[0] + red[1] + red[2] + red[3];
        s_inv = 1.0f / fmaxf(sqrtf(tot), 1e-12f);
    }
    __syncthreads();
    __hip_bfloat16 h = __float2bfloat16(x * s_inv);
    fhi[(size_t)row * DIM + tid] = *reinterpret_cast<ushort*>(&h);
}

// ---------------- Kernel B: fused tiled sim + mask + fixed-max softmax partials ----------------
// grid = 1024 blocks: chunk = bid&15 (512 cols), rowblk = bid>>4 (128 rows) -> 4 blocks/CU
// 8 waves, wave w owns rows rowblk*128 + w*16 .. +15, sweeps all 16 col-tiles of the chunk.
__global__ __launch_bounds__(512, 4) void main_kernel(const ushort* __restrict__ fhi,
                                                      const float* __restrict__ ious,
                                                      const int* __restrict__ labels,
                                                      float* __restrict__ ps_part,
                                                      float* __restrict__ as_part,
                                                      int* __restrict__ flag_part) {
    const int bid   = blockIdx.x;
    const int chunk = bid & (N_CHUNKS - 1);
    const int c0    = chunk * C_CHUNK;
    const int rbase = (bid >> 4) * R_BLK;

    const int tid  = threadIdx.x;
    const int lane = tid & 63;
    const int w    = tid >> 6;          // 0..7
    const int lrow = lane & 15;
    const int kg   = lane >> 4;         // 0..3
    const int r0   = rbase + w * 16;

    __shared__ ushort bt[2][TILE_C][DIM];   // 32 KB, double-buffered B tile
    __shared__ int    lab_s[C_CHUNK];       // 2 KB
    __shared__ float  iou_s[C_CHUNK];       // 2 KB

    // stage column metadata for this chunk
    {
        const int i = tid;
        if (i < C_CHUNK) {
            lab_s[i] = labels[c0 + i];
            iou_s[i] = ious[c0 + i];
        }
    }

    // A fragments: 16 rows x 256 k in registers (32 VGPR)
    bf16x8 av[8];
    {
        const ushort* pa = fhi + (size_t)(r0 + lrow) * DIM + kg * 8;
#pragma unroll
        for (int t = 0; t < 8; ++t) av[t] = *reinterpret_cast<const bf16x8*>(pa + t * 32);
    }

    // row metadata (C/D layout: col=lane&15, row=kg*4+reg)
    int labi[4]; float ioui[4]; bool fgi[4], hi_i[4], ng_i[4];
#pragma unroll
    for (int r = 0; r < 4; ++r) {
        int gi = r0 + kg * 4 + r;
        labi[r] = labels[gi];
        ioui[r] = ious[gi];
        fgi[r]  = labi[r] >= 0;
        hi_i[r] = ioui[r] > 0.5f;
        ng_i[r] = ioui[r] < 0.3f;
    }

    float ps[4] = {0.f, 0.f, 0.f, 0.f};
    float as_[4] = {0.f, 0.f, 0.f, 0.f};
    int apn = 0;   // bits 0-3: any-pos per r, bits 4-7: any-neg per r

    // staging: tile `it` -> buf; linear LDS dest, pre-swizzled global source (rule #21)
    const char* fhib = (const char*)fhi;
    char* btb = (char*)&bt[0][0][0];
    auto stage = [&](int buf, int it) {
        const int jc = c0 + it * TILE_C;
        const int kb = (tid & 31) * 16;
#pragma unroll
        for (int iss = 0; iss < 2; ++iss) {
            const int row = (tid >> 5) + iss * 16;          // tile-local col index
            const char* src = fhib + (((size_t)(jc + row)) << 9) + (kb ^ ((row & 7) << 4));
            char* dst = btb + buf * 16384 + iss * 8192 + tid * 16;
            gload_lds16(src, dst);
        }
    };

    stage(0, 0);
    __syncthreads();

    const float C1 = 14.42695041f;   // 10 * log2(e): e = exp2(acc*C1 - C1) == exp(sim - 10)
    int cur = 0;
    for (int it = 0; it < N_ITERS; ++it) {
        if (it + 1 < N_ITERS) stage(cur ^ 1, it + 1);

        const int jcl = it * TILE_C;
        const int labj0 = lab_s[jcl + lrow];
        const int labj1 = lab_s[jcl + 16 + lrow];
        const float iouj0 = iou_s[jcl + lrow];
        const float iouj1 = iou_s[jcl + 16 + lrow];

        f32x4 acc0 = {0.f, 0.f, 0.f, 0.f};
        f32x4 acc1 = {0.f, 0.f, 0.f, 0.f};
        const char* base = btb + cur * 16384;
        const int swz = (lrow & 7) << 4;
#pragma unroll
        for (int t = 0; t < 8; ++t) {
            const int koff = kg * 16 + t * 64;
            bf16x8 b0 = *reinterpret_cast<const bf16x8*>(base + lrow * 512 + (koff ^ swz));
            bf16x8 b1 = *reinterpret_cast<const bf16x8*>(base + (lrow + 16) * 512 + (koff ^ swz));
            acc0 = __builtin_amdgcn_mfma_f32_16x16x32_bf16(av[t], b0, acc0, 0, 0, 0);
            acc1 = __builtin_amdgcn_mfma_f32_16x16x32_bf16(av[t], b1, acc1, 0, 0, 0);
        }

        // epilogue: fixed max M=10 (sim <= 10 always); e = exp(sim-10)
#pragma unroll
        for (int half = 0; half < 2; ++half) {
            const int colg = c0 + jcl + half * 16 + lrow;
            const int labj = half ? labj1 : labj0;
            const float iouj = half ? iouj1 : iouj0;
            const f32x4 acc = half ? acc1 : acc0;
            const bool fgj = labj >= 0;
            const bool hij = iouj > 0.5f;
#pragma unroll
            for (int r = 0; r < 4; ++r) {
                const int gi = r0 + kg * 4 + r;
                const bool same = (labi[r] == labj);
                const bool ioum = hij && hi_i[r] && (fabsf(iouj - ioui[r]) < 0.2f);
                const bool pf   = fgi[r] && fgj && (gi != colg);
                const bool pos  = same && ioum && pf;
                const bool neg  = ((!same) || ng_i[r]) && pf;
                const bool allm = pos || neg;
                const float e = allm ? exp2f(fmaf(acc[r], C1, -C1)) : 0.0f;
                as_[r] += e;
                ps[r]  += pos ? e : 0.0f;
                apn |= (pos ? (1 << r) : 0) | (neg ? (1 << (r + 4)) : 0);
            }
        }
        __syncthreads();
        cur ^= 1;
    }

    // reduce over the 16 lanes (lrow) holding col-slices of the same rows
#pragma unroll
    for (int off = 1; off < 16; off <<= 1) {
#pragma unroll
        for (int r = 0; r < 4; ++r) {
            ps[r]  += __shfl_xor(ps[r], off);
            as_[r] += __shfl_xor(as_[r], off);
        }
        apn |= __shfl_xor(apn, off);
    }

    if (lrow == 0) {
#pragma unroll
        for (int r = 0; r < 4; ++r) {
            const int row = r0 + kg * 4 + r;
            const int idx = chunk * N_ROWS + row;
            ps_part[idx]   = ps[r];
            as_part[idx]   = as_[r];
            flag_part[idx] = ((apn >> r) & 1) | (((apn >> (r + 4)) & 1) << 1);
        }
    }
}

// ---------------- Kernel C: combine chunk partials -> per-row loss ----------------
__global__ __launch_bounds__(256) void combine_kernel(const float* __restrict__ ps_part,
                                                      const float* __restrict__ as_part,
                                                      const int* __restrict__ flag_part,
                                                      const int* __restrict__ labels,
                                                      float* __restrict__ loss_arr,
                                                      float* __restrict__ valid_arr) {
    const int row = blockIdx.x * 256 + threadIdx.x;
    float P = 0.f, A = 0.f; int f = 0;
#pragma unroll
    for (int c = 0; c < N_CHUNKS; ++c) {
        P += ps_part[c * N_ROWS + row];
        A += as_part[c * N_ROWS + row];
        f |= flag_part[c * N_ROWS + row];
    }
    const float psc = fminf(fmaxf(P, 1e-6f), 1e6f);
    const float asc = fminf(fmaxf(A, 1e-6f), 1e6f);
    const float loss = fminf(__logf(asc) - __logf(psc), 10.0f);
    const bool valid = (labels[row] >= 0) && (f & 1) && (f & 2);
    loss_arr[row]  = valid ? loss : 0.0f;
    valid_arr[row] = valid ? 1.0f : 0.0f;
}

// ---------------- Kernel D: final mean ----------------
__global__ __launch_bounds__(256) void reduce_kernel(const float* __restrict__ loss_arr,
                                                     const float* __restrict__ valid_arr,
                                                     float* __restrict__ out) {
    const int tid = threadIdx.x;
    float tl = 0.f, tc = 0.f;
    for (int i = tid; i < N_ROWS; i += 256) { tl += loss_arr[i]; tc += valid_arr[i]; }
#pragma unroll
    for (int off = 32; off; off >>= 1) { tl += __shfl_down(tl, off); tc += __shfl_down(tc, off); }
    __shared__ float sl[4], sc[4];
    const int wid = tid >> 6;
    if ((tid & 63) == 0) { sl[wid] = tl; sc[wid] = tc; }
    __syncthreads();
    if (tid == 0) {
        float T = sl[0] + sl[1] + sl[2] + sl[3];
        float C = sc[0] + sc[1] + sc[2] + sc[3];
        out[0] = (C > 0.f) ? (T / C) : 0.0f;
    }
}

extern "C" void kernel_launch(void* const* d_in, const int* in_sizes, int n_in,
                              void* d_out, int out_size, void* d_ws, size_t ws_size,
                              hipStream_t stream) {
    const float* feat   = (const float*)d_in[0];
    const float* ious   = (const float*)d_in[1];
    const int*   labels = (const int*)d_in[2];
    float* out = (float*)d_out;

    ushort* fhi = (ushort*)d_ws;                                   // 4 MB
    float*  ps_part = (float*)(fhi + (size_t)N_ROWS * DIM);        // 512 KB
    float*  as_part = ps_part + (size_t)N_CHUNKS * N_ROWS;         // 512 KB
    int*    flag_part = (int*)(as_part + (size_t)N_CHUNKS * N_ROWS); // 512 KB
    float*  loss_arr  = (float*)(flag_part + (size_t)N_CHUNKS * N_ROWS);
    float*  valid_arr = loss_arr + N_ROWS;

    prep_kernel<<<N_ROWS, 256, 0, stream>>>(feat, fhi);
    main_kernel<<<(N_ROWS / R_BLK) * N_CHUNKS, 512, 0, stream>>>(fhi, ious, labels,
                                                                 ps_part, as_part, flag_part);
    combine_kernel<<<N_ROWS / 256, 256, 0, stream>>>(ps_part, as_part, flag_part, labels,
                                                     loss_arr, valid_arr);
    reduce_kernel<<<1, 256, 0, stream>>>(loss_arr, valid_arr, out);
}

// Round 12
// 99.272 us; speedup vs baseline: 4.8108x; 1.0521x over previous
//
#include <hip/hip_runtime.h>
#include <hip/hip_bf16.h>

#define N_ROWS 8192
#define DIM 256
#define R_BLK 128          // rows per block (4 waves x 32 rows)
#define C_CHUNK 512        // cols per block
#define TILE_C 32          // cols per LDS tile
#define N_CHUNKS 16
#define N_ITERS (C_CHUNK / TILE_C)   // 16

typedef __attribute__((ext_vector_type(4))) float f32x4;
typedef __attribute__((ext_vector_type(8))) short bf16x8;

__device__ __forceinline__ void gload_lds16(const void* g, void* l) {
    using gv = const __attribute__((address_space(1))) void*;
    using sv = __attribute__((address_space(3))) void*;
    __builtin_amdgcn_global_load_lds((gv)g, (sv)l, 16, 0, 0);
}

// ---------------- Kernel A: normalize rows -> bf16 ----------------
__global__ __launch_bounds__(256) void prep_kernel(const float* __restrict__ feat,
                                                   ushort* __restrict__ fhi) {
    const int row = blockIdx.x;
    const int tid = threadIdx.x;
    float x = feat[(size_t)row * DIM + tid];
    float ss = x * x;
#pragma unroll
    for (int off = 32; off; off >>= 1) ss += __shfl_down(ss, off);
    __shared__ float red[4];
    __shared__ float s_inv;
    const int wid = tid >> 6;
    if ((tid & 63) == 0) red[wid] = ss;
    __syncthreads();
    if (tid == 0) {
        float tot = red[0] + red[1] + red[2] + red[3];
        s_inv = 1.0f / fmaxf(sqrtf(tot), 1e-12f);
    }
    __syncthreads();
    __hip_bfloat16 h = __float2bfloat16(x * s_inv);
    fhi[(size_t)row * DIM + tid] = *reinterpret_cast<ushort*>(&h);
}

// ---------------- Kernel B: fused tiled sim + mask + fixed-max softmax partials ----------------
// grid = 1024 blocks: chunk = bid&15 (512 cols), rowblk = bid>>4 (128 rows)
// 4 waves (256 thr), wave w owns 32 rows: r0 = rbase + w*32, two 16-row tiles.
__global__ __launch_bounds__(256, 3) void main_kernel(const ushort* __restrict__ fhi,
                                                      const float* __restrict__ ious,
                                                      const int* __restrict__ labels,
                                                      float* __restrict__ ps_part,
                                                      float* __restrict__ as_part) {
    const int bid   = blockIdx.x;
    const int chunk = bid & (N_CHUNKS - 1);
    const int c0    = chunk * C_CHUNK;
    const int rbase = (bid >> 4) * R_BLK;

    const int tid  = threadIdx.x;
    const int lane = tid & 63;
    const int w    = tid >> 6;          // 0..3
    const int lrow = lane & 15;
    const int kg   = lane >> 4;         // 0..3
    const int r0   = rbase + w * 32;

    __shared__ ushort bt[2][TILE_C][DIM];   // 32 KB, double-buffered B tile
    __shared__ int    lab_s[C_CHUNK];       // 2 KB
    __shared__ float  iou_s[C_CHUNK];       // 2 KB

    // stage column metadata for this chunk (2 per thread)
#pragma unroll
    for (int i = tid; i < C_CHUNK; i += 256) {
        lab_s[i] = labels[c0 + i];
        iou_s[i] = ious[c0 + i];
    }

    // A fragments: two 16-row tiles x 256 k in registers (64 VGPR)
    bf16x8 av0[8], av1[8];
    {
        const ushort* pa0 = fhi + (size_t)(r0 + lrow) * DIM + kg * 8;
        const ushort* pa1 = fhi + (size_t)(r0 + 16 + lrow) * DIM + kg * 8;
#pragma unroll
        for (int t = 0; t < 8; ++t) {
            av0[t] = *reinterpret_cast<const bf16x8*>(pa0 + t * 32);
            av1[t] = *reinterpret_cast<const bf16x8*>(pa1 + t * 32);
        }
    }

    // row metadata for the 8 rows this lane covers (C/D layout: col=lane&15, row=kg*4+reg)
    int labi[8]; float ioui[8]; bool fgi[8], hi_i[8], ng_i[8];
#pragma unroll
    for (int m = 0; m < 8; ++m) {
        const int rt = m >> 2, r = m & 3;
        const int gi = r0 + rt * 16 + kg * 4 + r;
        labi[m] = labels[gi];
        ioui[m] = ious[gi];
        fgi[m]  = labi[m] >= 0;
        hi_i[m] = ioui[m] > 0.5f;
        ng_i[m] = ioui[m] < 0.3f;
    }

    float ps[8], as_[8];
#pragma unroll
    for (int m = 0; m < 8; ++m) { ps[m] = 0.f; as_[m] = 0.f; }

    // staging: tile `it` -> buf; linear LDS dest, pre-swizzled global source (rule #21)
    const char* fhib = (const char*)fhi;
    char* btb = (char*)&bt[0][0][0];
    auto stage = [&](int buf, int it) {
        const int jc = c0 + it * TILE_C;
        const int kb = (tid & 31) * 16;
#pragma unroll
        for (int iss = 0; iss < 4; ++iss) {
            const int row = (tid >> 5) + iss * 8;           // tile-local col index 0..31
            const char* src = fhib + (((size_t)(jc + row)) << 9) + (kb ^ ((row & 7) << 4));
            char* dst = btb + buf * 16384 + iss * 4096 + tid * 16;
            gload_lds16(src, dst);
        }
    };

    stage(0, 0);
    __syncthreads();

    const float C1 = 14.42695041f;   // 10*log2(e): e = exp2(acc*C1 - C1) == exp(sim-10)
    int cur = 0;
    for (int it = 0; it < N_ITERS; ++it) {
        if (it + 1 < N_ITERS) stage(cur ^ 1, it + 1);

        const int jcl = it * TILE_C;
        const int labj0 = lab_s[jcl + lrow];
        const int labj1 = lab_s[jcl + 16 + lrow];
        const float iouj0 = iou_s[jcl + lrow];
        const float iouj1 = iou_s[jcl + 16 + lrow];

        f32x4 acc00 = {0.f,0.f,0.f,0.f}, acc01 = {0.f,0.f,0.f,0.f};
        f32x4 acc10 = {0.f,0.f,0.f,0.f}, acc11 = {0.f,0.f,0.f,0.f};
        const char* base = btb + cur * 16384;
        const int swz = (lrow & 7) << 4;
#pragma unroll
        for (int t = 0; t < 8; ++t) {
            const int koff = kg * 16 + t * 64;
            bf16x8 b0 = *reinterpret_cast<const bf16x8*>(base + lrow * 512 + (koff ^ swz));
            bf16x8 b1 = *reinterpret_cast<const bf16x8*>(base + (lrow + 16) * 512 + (koff ^ swz));
            acc00 = __builtin_amdgcn_mfma_f32_16x16x32_bf16(av0[t], b0, acc00, 0, 0, 0);
            acc01 = __builtin_amdgcn_mfma_f32_16x16x32_bf16(av0[t], b1, acc01, 0, 0, 0);
            acc10 = __builtin_amdgcn_mfma_f32_16x16x32_bf16(av1[t], b0, acc10, 0, 0, 0);
            acc11 = __builtin_amdgcn_mfma_f32_16x16x32_bf16(av1[t], b1, acc11, 0, 0, 0);
        }

        // epilogue: fixed max M=10 (sim<=10 always); e = exp(sim-10); no flag tracking
#pragma unroll
        for (int rt = 0; rt < 2; ++rt) {
#pragma unroll
            for (int half = 0; half < 2; ++half) {
                const int colg = c0 + jcl + half * 16 + lrow;
                const int labj = half ? labj1 : labj0;
                const float iouj = half ? iouj1 : iouj0;
                const f32x4 acc = rt ? (half ? acc11 : acc10) : (half ? acc01 : acc00);
                const bool fgj = labj >= 0;
                const bool hij = iouj > 0.5f;
#pragma unroll
                for (int r = 0; r < 4; ++r) {
                    const int m  = rt * 4 + r;
                    const int gi = r0 + rt * 16 + kg * 4 + r;
                    const bool same = (labi[m] == labj);
                    const bool ioum = hij && hi_i[m] && (fabsf(iouj - ioui[m]) < 0.2f);
                    const bool pf   = fgi[m] && fgj && (gi != colg);
                    const bool pos  = same && ioum && pf;
                    const bool neg  = ((!same) || ng_i[m]) && pf;
                    const float e = (pos || neg) ? exp2f(fmaf(acc[r], C1, -C1)) : 0.0f;
                    as_[m] += e;
                    ps[m]  += pos ? e : 0.0f;
                }
            }
        }
        __syncthreads();
        cur ^= 1;
    }

    // reduce over the 16 lanes (lrow) holding col-slices of the same rows
#pragma unroll
    for (int off = 1; off < 16; off <<= 1) {
#pragma unroll
        for (int m = 0; m < 8; ++m) {
            ps[m]  += __shfl_xor(ps[m], off);
            as_[m] += __shfl_xor(as_[m], off);
        }
    }

    if (lrow == 0) {
#pragma unroll
        for (int m = 0; m < 8; ++m) {
            const int rt = m >> 2, r = m & 3;
            const int row = r0 + rt * 16 + kg * 4 + r;
            const int idx = chunk * N_ROWS + row;
            ps_part[idx] = ps[m];
            as_part[idx] = as_[m];
        }
    }
}

// ---------------- Kernel C: combine chunk partials -> per-row loss ----------------
// any-pos <=> P>0 ; any-neg <=> A>P (pos and neg are disjoint: iou<0.3 && iou>0.5 impossible)
__global__ __launch_bounds__(256) void combine_kernel(const float* __restrict__ ps_part,
                                                      const float* __restrict__ as_part,
                                                      const int* __restrict__ labels,
                                                      float* __restrict__ loss_arr,
                                                      float* __restrict__ valid_arr) {
    const int row = blockIdx.x * 256 + threadIdx.x;
    float P = 0.f, A = 0.f;
#pragma unroll
    for (int c = 0; c < N_CHUNKS; ++c) {
        P += ps_part[c * N_ROWS + row];
        A += as_part[c * N_ROWS + row];
    }
    const float psc = fminf(fmaxf(P, 1e-6f), 1e6f);
    const float asc = fminf(fmaxf(A, 1e-6f), 1e6f);
    const float loss = fminf(__logf(asc) - __logf(psc), 10.0f);
    const bool valid = (labels[row] >= 0) && (P > 0.0f) && (A > P);
    loss_arr[row]  = valid ? loss : 0.0f;
    valid_arr[row] = valid ? 1.0f : 0.0f;
}

// ---------------- Kernel D: final mean ----------------
__global__ __launch_bounds__(256) void reduce_kernel(const float* __restrict__ loss_arr,
                                                     const float* __restrict__ valid_arr,
                                                     float* __restrict__ out) {
    const int tid = threadIdx.x;
    float tl = 0.f, tc = 0.f;
    for (int i = tid; i < N_ROWS; i += 256) { tl += loss_arr[i]; tc += valid_arr[i]; }
#pragma unroll
    for (int off = 32; off; off >>= 1) { tl += __shfl_down(tl, off); tc += __shfl_down(tc, off); }
    __shared__ float sl[4], sc[4];
    const int wid = tid >> 6;
    if ((tid & 63) == 0) { sl[wid] = tl; sc[wid] = tc; }
    __syncthreads();
    if (tid == 0) {
        float T = sl[0] + sl[1] + sl[2] + sl[3];
        float C = sc[0] + sc[1] + sc[2] + sc[3];
        out[0] = (C > 0.f) ? (T / C) : 0.0f;
    }
}

extern "C" void kernel_launch(void* const* d_in, const int* in_sizes, int n_in,
                              void* d_out, int out_size, void* d_ws, size_t ws_size,
                              hipStream_t stream) {
    const float* feat   = (const float*)d_in[0];
    const float* ious   = (const float*)d_in[1];
    const int*   labels = (const int*)d_in[2];
    float* out = (float*)d_out;

    ushort* fhi = (ushort*)d_ws;                                   // 4 MB
    float*  ps_part = (float*)(fhi + (size_t)N_ROWS * DIM);        // 512 KB
    float*  as_part = ps_part + (size_t)N_CHUNKS * N_ROWS;         // 512 KB
    float*  loss_arr  = as_part + (size_t)N_CHUNKS * N_ROWS;
    float*  valid_arr = loss_arr + N_ROWS;

    prep_kernel<<<N_ROWS, 256, 0, stream>>>(feat, fhi);
    main_kernel<<<(N_ROWS / R_BLK) * N_CHUNKS, 256, 0, stream>>>(fhi, ious, labels,
                                                                 ps_part, as_part);
    combine_kernel<<<N_ROWS / 256, 256, 0, stream>>>(ps_part, as_part, labels,
                                                     loss_arr, valid_arr);
    reduce_kernel<<<1, 256, 0, stream>>>(loss_arr, valid_arr, out);
}

// Round 13
// 74.654 us; speedup vs baseline: 6.3972x; 1.3298x over previous
//
#include <hip/hip_runtime.h>
#include <hip/hip_bf16.h>

#define N_ROWS 8192
#define DIM 256
#define R_BLK 128          // row-slots per block (4 waves x 32)
#define C_CHUNK 512        // cols per block
#define TILE_C 32          // cols per LDS tile
#define N_CHUNKS 16
#define N_ITERS (C_CHUNK / TILE_C)   // 16

typedef __attribute__((ext_vector_type(4))) float f32x4;
typedef __attribute__((ext_vector_type(8))) short bf16x8;

__device__ __forceinline__ void gload_lds16(const void* g, void* l) {
    using gv = const __attribute__((address_space(1))) void*;
    using sv = __attribute__((address_space(3))) void*;
    __builtin_amdgcn_global_load_lds((gv)g, (sv)l, 16, 0, 0);
}

__device__ __forceinline__ ushort f2bf(float v) {
    __hip_bfloat16 h = __float2bfloat16(v);
    return *reinterpret_cast<ushort*>(&h);
}

// ---------------- Kernel A: normalize rows -> bf16 (1 wave per row, no LDS) ----------------
__global__ __launch_bounds__(256) void prep_kernel(const float* __restrict__ feat,
                                                   ushort* __restrict__ fhi) {
    const int row  = blockIdx.x * 4 + (threadIdx.x >> 6);
    const int lane = threadIdx.x & 63;
    const float4 x = reinterpret_cast<const float4*>(feat + (size_t)row * DIM)[lane];
    float ss = x.x * x.x + x.y * x.y + x.z * x.z + x.w * x.w;
#pragma unroll
    for (int off = 32; off; off >>= 1) ss += __shfl_xor(ss, off);
    const float inv = 1.0f / fmaxf(sqrtf(ss), 1e-12f);
    ushort4 h;
    h.x = f2bf(x.x * inv); h.y = f2bf(x.y * inv);
    h.z = f2bf(x.z * inv); h.w = f2bf(x.w * inv);
    reinterpret_cast<ushort4*>(fhi + (size_t)row * DIM)[lane] = h;
}

// ---------------- Kernel A2: compact active rows (label>=0 && iou>0.5) ----------------
// Single block; order within ridx is non-deterministic but per-row results are
// slot-independent and outputs are indexed by original row id -> deterministic.
__global__ __launch_bounds__(256) void compact_kernel(const float* __restrict__ ious,
                                                      const int* __restrict__ labels,
                                                      int* __restrict__ ridx,
                                                      int* __restrict__ nact) {
    __shared__ int cnt;
    if (threadIdx.x == 0) cnt = 0;
    __syncthreads();
    const int lane = threadIdx.x & 63;
    for (int i = threadIdx.x; i < N_ROWS; i += 256) {
        const bool act = (labels[i] >= 0) && (ious[i] > 0.5f);
        const unsigned long long mb = __ballot(act);
        const int off = __popcll(mb & ((1ull << lane) - 1ull));
        const int tot = __popcll(mb);
        int base = 0;
        if (lane == 0 && tot) base = atomicAdd(&cnt, tot);
        base = __shfl(base, 0);
        if (act) ridx[base + off] = i;
    }
    __syncthreads();
    if (threadIdx.x == 0) nact[0] = cnt;
}

// ---------------- Kernel B: fused tiled sim + mask + fixed-max softmax partials ----------------
// grid = 1024 blocks: chunk = bid&15 (512 cols), rowblk = bid>>4 (128 active-row slots)
// Blocks whose slot range is beyond nact exit immediately (~half the grid).
// Active rows have iou>0.5 & fg -> hi_i always true, ng_i always false.
__global__ __launch_bounds__(256, 3) void main_kernel(const ushort* __restrict__ fhi,
                                                      const float* __restrict__ ious,
                                                      const int* __restrict__ labels,
                                                      const int* __restrict__ ridx,
                                                      const int* __restrict__ nact,
                                                      float* __restrict__ ps_part,
                                                      float* __restrict__ as_part) {
    const int nactive = nact[0];
    const int bid   = blockIdx.x;
    const int rbase = (bid >> 4) * R_BLK;
    if (rbase >= nactive) return;      // uniform early-exit, before any barrier

    const int chunk = bid & (N_CHUNKS - 1);
    const int c0    = chunk * C_CHUNK;

    const int tid  = threadIdx.x;
    const int lane = tid & 63;
    const int w    = tid >> 6;          // 0..3
    const int lrow = lane & 15;
    const int kg   = lane >> 4;         // 0..3
    const int s0   = rbase + w * 32;    // this wave's first row-slot

    __shared__ ushort bt[2][TILE_C][DIM];   // 32 KB, double-buffered B tile
    __shared__ int    lab_s[C_CHUNK];       // 2 KB
    __shared__ float  iou_s[C_CHUNK];       // 2 KB

    // stage column metadata for this chunk (2 per thread)
#pragma unroll
    for (int i = tid; i < C_CHUNK; i += 256) {
        lab_s[i] = labels[c0 + i];
        iou_s[i] = ious[c0 + i];
    }

    // A fragments: two 16-row tiles (gathered via ridx) x 256 k in registers
    bf16x8 av0[8], av1[8];
    {
        const int rowA0 = ridx[min(s0 + lrow,      nactive - 1)];
        const int rowA1 = ridx[min(s0 + 16 + lrow, nactive - 1)];
        const ushort* pa0 = fhi + (size_t)rowA0 * DIM + kg * 8;
        const ushort* pa1 = fhi + (size_t)rowA1 * DIM + kg * 8;
#pragma unroll
        for (int t = 0; t < 8; ++t) {
            av0[t] = *reinterpret_cast<const bf16x8*>(pa0 + t * 32);
            av1[t] = *reinterpret_cast<const bf16x8*>(pa1 + t * 32);
        }
    }

    // row metadata for the 8 row-slots this lane covers (C/D: col=lane&15, row=kg*4+reg)
    int rowm[8]; int labi[8]; float ioui[8]; bool live[8];
#pragma unroll
    for (int m = 0; m < 8; ++m) {
        const int rt = m >> 2, r = m & 3;
        const int slot = s0 + rt * 16 + kg * 4 + r;
        live[m] = slot < nactive;
        const int gi = ridx[min(slot, nactive - 1)];
        rowm[m] = gi;
        labi[m] = live[m] ? labels[gi] : -2;   // -2: matches no column label
        ioui[m] = ious[gi];
    }

    float ps[8], as_[8];
#pragma unroll
    for (int m = 0; m < 8; ++m) { ps[m] = 0.f; as_[m] = 0.f; }

    // staging: tile `it` -> buf; linear LDS dest, pre-swizzled global source (rule #21)
    const char* fhib = (const char*)fhi;
    char* btb = (char*)&bt[0][0][0];
    auto stage = [&](int buf, int it) {
        const int jc = c0 + it * TILE_C;
        const int kb = (tid & 31) * 16;
#pragma unroll
        for (int iss = 0; iss < 4; ++iss) {
            const int row = (tid >> 5) + iss * 8;           // tile-local col 0..31
            const char* src = fhib + (((size_t)(jc + row)) << 9) + (kb ^ ((row & 7) << 4));
            char* dst = btb + buf * 16384 + iss * 4096 + tid * 16;
            gload_lds16(src, dst);
        }
    };

    stage(0, 0);
    __syncthreads();

    const float C1 = 14.42695041f;   // 10*log2(e): e = exp2(acc*C1 - C1) == exp(sim-10)
    int cur = 0;
    for (int it = 0; it < N_ITERS; ++it) {
        if (it + 1 < N_ITERS) stage(cur ^ 1, it + 1);

        const int jcl = it * TILE_C;
        const int labj0 = lab_s[jcl + lrow];
        const int labj1 = lab_s[jcl + 16 + lrow];
        const float iouj0 = iou_s[jcl + lrow];
        const float iouj1 = iou_s[jcl + 16 + lrow];

        f32x4 acc00 = {0.f,0.f,0.f,0.f}, acc01 = {0.f,0.f,0.f,0.f};
        f32x4 acc10 = {0.f,0.f,0.f,0.f}, acc11 = {0.f,0.f,0.f,0.f};
        const char* base = btb + cur * 16384;
        const int swz = (lrow & 7) << 4;
#pragma unroll
        for (int t = 0; t < 8; ++t) {
            const int koff = kg * 16 + t * 64;
            bf16x8 b0 = *reinterpret_cast<const bf16x8*>(base + lrow * 512 + (koff ^ swz));
            bf16x8 b1 = *reinterpret_cast<const bf16x8*>(base + (lrow + 16) * 512 + (koff ^ swz));
            acc00 = __builtin_amdgcn_mfma_f32_16x16x32_bf16(av0[t], b0, acc00, 0, 0, 0);
            acc01 = __builtin_amdgcn_mfma_f32_16x16x32_bf16(av0[t], b1, acc01, 0, 0, 0);
            acc10 = __builtin_amdgcn_mfma_f32_16x16x32_bf16(av1[t], b0, acc10, 0, 0, 0);
            acc11 = __builtin_amdgcn_mfma_f32_16x16x32_bf16(av1[t], b1, acc11, 0, 0, 0);
        }

        // epilogue (active rows: hi_i true, ng_i false, fg_i true):
        //   pos = same && iouj>0.5 && |d|<0.2 && fgj && i!=j
        //   neg = !same && fgj && i!=j ;  allm = (fgj && i!=j) && (ioum || !same)
#pragma unroll
        for (int rt = 0; rt < 2; ++rt) {
#pragma unroll
            for (int half = 0; half < 2; ++half) {
                const int colg = c0 + jcl + half * 16 + lrow;
                const int labj = half ? labj1 : labj0;
                const float iouj = half ? iouj1 : iouj0;
                const f32x4 acc = rt ? (half ? acc11 : acc10) : (half ? acc01 : acc00);
                const bool fgj = labj >= 0;
                const bool hij = iouj > 0.5f;
#pragma unroll
                for (int r = 0; r < 4; ++r) {
                    const int m  = rt * 4 + r;
                    const bool same = (labi[m] == labj);
                    const bool ioum = hij && (fabsf(iouj - ioui[m]) < 0.2f);
                    const bool pf   = fgj && (rowm[m] != colg);
                    const bool pos  = same && ioum && pf;
                    const bool allm = pf && (ioum || !same);
                    const float e = allm ? exp2f(fmaf(acc[r], C1, -C1)) : 0.0f;
                    as_[m] += e;
                    ps[m]  += pos ? e : 0.0f;
                }
            }
        }
        __syncthreads();
        cur ^= 1;
    }

    // reduce over the 16 lanes (lrow) holding col-slices of the same rows
#pragma unroll
    for (int off = 1; off < 16; off <<= 1) {
#pragma unroll
        for (int m = 0; m < 8; ++m) {
            ps[m]  += __shfl_xor(ps[m], off);
            as_[m] += __shfl_xor(as_[m], off);
        }
    }

    if (lrow == 0) {
#pragma unroll
        for (int m = 0; m < 8; ++m) {
            if (live[m]) {
                const int idx = chunk * N_ROWS + rowm[m];
                ps_part[idx] = ps[m];
                as_part[idx] = as_[m];
            }
        }
    }
}

// ---------------- Kernel C: combine chunk partials -> per-row loss ----------------
// Only rows with (label>=0 && iou>0.5) have written partials; others are gated off.
// any-pos <=> P>0 ; any-neg <=> A>P (pos/neg disjoint for active rows: neg needs !same, pos needs same)
__global__ __launch_bounds__(256) void combine_kernel(const float* __restrict__ ps_part,
                                                      const float* __restrict__ as_part,
                                                      const float* __restrict__ ious,
                                                      const int* __restrict__ labels,
                                                      float* __restrict__ loss_arr,
                                                      float* __restrict__ valid_arr) {
    const int row = blockIdx.x * 256 + threadIdx.x;
    const bool act = (labels[row] >= 0) && (ious[row] > 0.5f);
    float loss = 0.f, vld = 0.f;
    if (act) {
        float P = 0.f, A = 0.f;
#pragma unroll
        for (int c = 0; c < N_CHUNKS; ++c) {
            P += ps_part[c * N_ROWS + row];
            A += as_part[c * N_ROWS + row];
        }
        const float psc = fminf(fmaxf(P, 1e-6f), 1e6f);
        const float asc = fminf(fmaxf(A, 1e-6f), 1e6f);
        const bool valid = (P > 0.0f) && (A > P);
        loss = valid ? fminf(__logf(asc) - __logf(psc), 10.0f) : 0.0f;
        vld  = valid ? 1.0f : 0.0f;
    }
    loss_arr[row]  = loss;
    valid_arr[row] = vld;
}

// ---------------- Kernel D: final mean ----------------
__global__ __launch_bounds__(256) void reduce_kernel(const float* __restrict__ loss_arr,
                                                     const float* __restrict__ valid_arr,
                                                     float* __restrict__ out) {
    const int tid = threadIdx.x;
    float tl = 0.f, tc = 0.f;
    for (int i = tid; i < N_ROWS; i += 256) { tl += loss_arr[i]; tc += valid_arr[i]; }
#pragma unroll
    for (int off = 32; off; off >>= 1) { tl += __shfl_down(tl, off); tc += __shfl_down(tc, off); }
    __shared__ float sl[4], sc[4];
    const int wid = tid >> 6;
    if ((tid & 63) == 0) { sl[wid] = tl; sc[wid] = tc; }
    __syncthreads();
    if (tid == 0) {
        float T = sl[0] + sl[1] + sl[2] + sl[3];
        float C = sc[0] + sc[1] + sc[2] + sc[3];
        out[0] = (C > 0.f) ? (T / C) : 0.0f;
    }
}

extern "C" void kernel_launch(void* const* d_in, const int* in_sizes, int n_in,
                              void* d_out, int out_size, void* d_ws, size_t ws_size,
                              hipStream_t stream) {
    const float* feat   = (const float*)d_in[0];
    const float* ious   = (const float*)d_in[1];
    const int*   labels = (const int*)d_in[2];
    float* out = (float*)d_out;

    ushort* fhi = (ushort*)d_ws;                                     // 4 MB
    float*  ps_part = (float*)(fhi + (size_t)N_ROWS * DIM);          // 512 KB
    float*  as_part = ps_part + (size_t)N_CHUNKS * N_ROWS;           // 512 KB
    float*  loss_arr  = as_part + (size_t)N_CHUNKS * N_ROWS;         // 32 KB
    float*  valid_arr = loss_arr + N_ROWS;                           // 32 KB
    int*    ridx = (int*)(valid_arr + N_ROWS);                       // 32 KB
    int*    nact = ridx + N_ROWS;                                    // 4 B

    prep_kernel<<<N_ROWS / 4, 256, 0, stream>>>(feat, fhi);
    compact_kernel<<<1, 256, 0, stream>>>(ious, labels, ridx, nact);
    main_kernel<<<(N_ROWS / R_BLK) * N_CHUNKS, 256, 0, stream>>>(fhi, ious, labels,
                                                                 ridx, nact, ps_part, as_part);
    combine_kernel<<<N_ROWS / 256, 256, 0, stream>>>(ps_part, as_part, ious, labels,
                                                     loss_arr, valid_arr);
    reduce_kernel<<<1, 256, 0, stream>>>(loss_arr, valid_arr, out);
}